// Round 8
// baseline (121.199 us; speedup 1.0000x reference)
//
#include <hip/hip_runtime.h>
#include <hip/hip_bf16.h>
#include <math.h>

#define CNUM 20
#define KNUM 64
#define DDIM 256
#define SEGS 8

typedef __attribute__((ext_vector_type(8))) short short8;
typedef __attribute__((ext_vector_type(4))) unsigned short u16x4;
typedef __attribute__((ext_vector_type(4))) float f32x4;

static __device__ __forceinline__ float shfl_xor_f(float v, int m) {
    return __shfl_xor(v, m, 64);
}

static __device__ __forceinline__ unsigned short f2bf(float f) {
    union { float f; unsigned u; } x; x.f = f;
    unsigned r = x.u + 0x7FFF + ((x.u >> 16) & 1);   // RTN-even
    return (unsigned short)(r >> 16);
}

static __device__ __forceinline__ float bf2f(unsigned short h) {
    union { unsigned u; float f; } x; x.u = ((unsigned)h) << 16;
    return x.f;
}

// ---- K_A: fused setup. blocks [0,320): per-(c,k) stats + mu->bf16 (4 ck/block);
// ----      blocks [320,320+SNB): per-scatter-block label histogram ----
__global__ void k_setup(const float* __restrict__ mu, const float* __restrict__ exp_temp,
                        const float* __restrict__ runa, const float* __restrict__ runb,
                        const float* __restrict__ med, const float* __restrict__ stdv,
                        const int* __restrict__ labels, int N,
                        float* __restrict__ mu2, float* __restrict__ rtau,
                        float* __restrict__ ltau, float* __restrict__ vldf,
                        float* __restrict__ rstd, float* __restrict__ mrs,
                        unsigned short* __restrict__ mubf, int* __restrict__ bc)
{
    __shared__ int h[CNUM];
    const int bid = blockIdx.x, tid = threadIdx.x;
    if (bid < 320) {
        const int w = tid >> 6, lane = tid & 63;
        if (bid == 0) {
            const float r = 1.0f / stdv[tid];           // blockDim==DDIM==256
            rstd[tid] = r;
            mrs[tid] = med[tid] * r;
        }
        const int ck = bid * 4 + w;                      // covers [0, 1280)
        const float4 v = *(const float4*)(mu + (size_t)ck * DDIM + lane * 4);
        u16x4 pk;
        pk[0] = f2bf(v.x); pk[1] = f2bf(v.y); pk[2] = f2bf(v.z); pk[3] = f2bf(v.w);
        *(u16x4*)(mubf + (size_t)ck * DDIM + lane * 4) = pk;
        float s = v.x * v.x + v.y * v.y + v.z * v.z + v.w * v.w;
#pragma unroll
        for (int off = 32; off > 0; off >>= 1) s += shfl_xor_f(s, off);
        if (lane == 0) {
            mu2[ck] = s;
            const float e = exp_temp[ck];
            const float t = 100.0f / (1.0f + __expf(-0.5f * e)) + 0.01f;
            rtau[ck] = 1.0f / t;
            ltau[ck] = logf(t);
            const int c = ck >> 6;
            const float thr = runb[c] * (0.5f / (float)KNUM);
            vldf[ck] = (runa[ck] > thr) ? 1.0f : 0.0f;
        }
    } else {
        const int hb = bid - 320;                        // one histogram per 256 samples
        if (tid < CNUM) h[tid] = 0;
        __syncthreads();
        const int i = hb * 256 + tid;
        if (i < N) atomicAdd(&h[labels[i]], 1);
        __syncthreads();
        if (tid < CNUM) bc[hb * CNUM + tid] = h[tid];
    }
}

// ---- K_B: counts, padded offsets, per-block scatter bases, block->class map ----
__global__ void k_scan(const int* __restrict__ bc, int snb, int* __restrict__ cnt,
                       int* __restrict__ ps, int* __restrict__ sb,
                       int* __restrict__ blk2cls)
{
    __shared__ int part[SEGS][CNUM];
    __shared__ int psl[CNUM + 1];
    const int tid = threadIdx.x;
    const int spb = (snb + SEGS - 1) / SEGS;
    if (tid < SEGS * CNUM) {
        const int c = tid % CNUM, seg = tid / CNUM;
        const int b0 = seg * spb, b1 = min(b0 + spb, snb);
        int s = 0;
        for (int b = b0; b < b1; ++b) s += bc[b * CNUM + c];
        part[seg][c] = s;
    }
    __syncthreads();
    if (tid < CNUM) {
        int s = 0;
#pragma unroll
        for (int g = 0; g < SEGS; ++g) s += part[g][tid];
        cnt[tid] = s;
    }
    __syncthreads();
    if (tid == 0) {
        int run = 0;
        for (int c = 0; c < CNUM; ++c) {
            psl[c] = run; ps[c] = run;
            run += (cnt[c] + 63) & ~63;
        }
        psl[CNUM] = run; ps[CNUM] = run;
    }
    __syncthreads();
    if (tid < SEGS * CNUM) {
        const int c = tid % CNUM, seg = tid / CNUM;
        int run = psl[c];
        for (int g = 0; g < seg; ++g) run += part[g][c];
        const int b0 = seg * spb, b1 = min(b0 + spb, snb);
        for (int b = b0; b < b1; ++b) { sb[b * CNUM + c] = run; run += bc[b * CNUM + c]; }
    }
    __syncthreads();
    if (tid < CNUM) {
        const int b0 = psl[tid] >> 6, b1 = psl[tid + 1] >> 6;
        for (int b = b0; b < b1; ++b) blk2cls[b] = tid;
    }
}

// ---- K_C: sequential read + normalize + bf16 pack + SCATTER-write to class-sorted xs.
// ----      Reads are fully coalesced & sequential; scattered 512B writes don't stall. ----
__global__ __launch_bounds__(256, 4)
void k_scnorm(const float* __restrict__ data, const float* __restrict__ mrs,
              const float* __restrict__ rstd, const int* __restrict__ labels, int N,
              const int* __restrict__ sb, unsigned short* __restrict__ xs)
{
    __shared__ int cur[CNUM];
    __shared__ int prank[256];
    const int tid = threadIdx.x, w = tid >> 6, lane = tid & 63;
    const int base = blockIdx.x * 256;
    if (tid < CNUM) cur[tid] = sb[blockIdx.x * CNUM + tid];
    __syncthreads();
    if (base + tid < N) prank[tid] = atomicAdd(&cur[labels[base + tid]], 1);
    __syncthreads();

    const float4 m4 = *(const float4*)(mrs + 4 * lane);
    const float4 r4 = *(const float4*)(rstd + 4 * lane);
    const float* __restrict__ src0 = data + (size_t)(base + 64 * w) * DDIM + 4 * lane;
    const int nrow = min(64, N - (base + 64 * w));
    if (nrow == 64) {
#pragma unroll 1
        for (int j = 0; j < 64; j += 4) {
            // 4 independent 1KB row-reads in flight
            const float4 u0 = *(const float4*)(src0 + (size_t)(j + 0) * DDIM);
            const float4 u1 = *(const float4*)(src0 + (size_t)(j + 1) * DDIM);
            const float4 u2 = *(const float4*)(src0 + (size_t)(j + 2) * DDIM);
            const float4 u3 = *(const float4*)(src0 + (size_t)(j + 3) * DDIM);
#pragma unroll
            for (int t = 0; t < 4; ++t) {
                const float4 u = (t == 0) ? u0 : (t == 1) ? u1 : (t == 2) ? u2 : u3;
                const int p = prank[64 * w + j + t];
                union { uint2 u2v; __hip_bfloat162 b2[2]; } pk;
                pk.b2[0] = __float22bfloat162_rn(
                    float2{fmaf(u.x, r4.x, -m4.x), fmaf(u.y, r4.y, -m4.y)});
                pk.b2[1] = __float22bfloat162_rn(
                    float2{fmaf(u.z, r4.z, -m4.z), fmaf(u.w, r4.w, -m4.w)});
                *(uint2*)((unsigned char*)xs + (size_t)p * 512 + 8 * lane) = pk.u2v;
            }
        }
    } else {
        for (int j = 0; j < nrow; ++j) {
            const float4 u = *(const float4*)(src0 + (size_t)j * DDIM);
            const int p = prank[64 * w + j];
            union { uint2 u2v; __hip_bfloat162 b2[2]; } pk;
            pk.b2[0] = __float22bfloat162_rn(
                float2{fmaf(u.x, r4.x, -m4.x), fmaf(u.y, r4.y, -m4.y)});
            pk.b2[1] = __float22bfloat162_rn(
                float2{fmaf(u.z, r4.z, -m4.z), fmaf(u.w, r4.w, -m4.w)});
            *(uint2*)((unsigned char*)xs + (size_t)p * 512 + 8 * lane) = pk.u2v;
        }
    }
}

// ---- K_D: MFMA — X slice (contig 32KB) + class-mu tile (32KB) staged via
// ----      global_load_lds with XOR source-pre-swizzle; conflict-free b128 reads. ----
__global__ __launch_bounds__(256, 2)
void k_mfma(const unsigned short* __restrict__ xs, const unsigned short* __restrict__ mubf,
            const float* __restrict__ mu2, const float* __restrict__ rtau,
            const float* __restrict__ ltau, const float* __restrict__ vldf,
            const int* __restrict__ ps, const int* __restrict__ cnt,
            const int* __restrict__ blk2cls, float* __restrict__ wpart)
{
    __shared__ __align__(16) unsigned char Xb[64 * 512];   // bf16 rows, swizzled
    __shared__ __align__(16) unsigned char Ub[64 * 512];
    const int tid = threadIdx.x, w = tid >> 6, lane = tid & 63;
    const int g = blockIdx.x;
    const int slot0 = g * 64;
    const int padtot = ps[CNUM];
    if (slot0 >= padtot) { if (lane == 0) wpart[g * 4 + w] = 0.f; return; }
    const int c = blk2cls[g];
    const int relast = ps[c] + cnt[c] - 1;

    const int h2 = lane >> 5;
    const int m31b = 16 * (lane & 31);
    // stage: 8 instr X + 8 instr MU per wave, 2 rows (1KB) each, sources sequential
#pragma unroll
    for (int pr = 0; pr < 8; ++pr) {
        const int lr = 16 * w + 2 * pr + h2;             // local row 0..63
        const int sw = 16 * (lr & 7);
        const unsigned char* sx = (const unsigned char*)xs
            + (size_t)(slot0 + lr) * 512 + (m31b ^ sw);
        const unsigned char* sm = (const unsigned char*)mubf
            + ((size_t)c * KNUM + lr) * 512 + (m31b ^ sw);
        void* dx = (void*)(Xb + (size_t)(16 * w + 2 * pr) * 512);
        void* dm = (void*)(Ub + (size_t)(16 * w + 2 * pr) * 512);
        __builtin_amdgcn_global_load_lds(
            (const __attribute__((address_space(1))) void*)sx,
            (__attribute__((address_space(3))) void*)dx, 16, 0, 0);
        __builtin_amdgcn_global_load_lds(
            (const __attribute__((address_space(1))) void*)sm,
            (__attribute__((address_space(3))) void*)dm, 16, 0, 0);
    }
    asm volatile("s_waitcnt vmcnt(0)" ::: "memory");
    __syncthreads();                                     // mu tile shared across waves

    const int n16 = lane & 15, kg = lane >> 4;
    const int Sb = 16 * (n16 & 7);
    const unsigned char* __restrict__ xrd = Xb + (size_t)(16 * w + n16) * 512;

    short8 xb[8];
#pragma unroll
    for (int s = 0; s < 8; ++s)
        xb[s] = *(const short8*)(xrd + ((64 * s + 16 * kg) ^ Sb));

    f32x4 acc[4] = {};
#pragma unroll
    for (int s = 0; s < 8; ++s) {
        short8 af[4];
#pragma unroll
        for (int f = 0; f < 4; ++f)
            af[f] = *(const short8*)(Ub + (size_t)(16 * f + n16) * 512
                                        + ((64 * s + 16 * kg) ^ Sb));
#pragma unroll
        for (int f = 0; f < 4; ++f)
            acc[f] = __builtin_amdgcn_mfma_f32_16x16x32_bf16(af[f], xb[s], acc[f], 0, 0, 0);
    }

    // |x|^2 from the bf16 fragments (consistent with the dot)
    float q = 0.f;
#pragma unroll
    for (int s = 0; s < 8; ++s)
#pragma unroll
        for (int j = 0; j < 8; ++j) {
            const float f = bf2f((unsigned short)xb[s][j]);
            q = fmaf(f, f, q);
        }
    q += shfl_xor_f(q, 16);
    q += shfl_xor_f(q, 32);

    // epilogue: lane holds 16 k-values (k = 16f + 4kg + r) of its sample
    const int ckb = c * KNUM;
    float simv[16], lpv[16];
    float mxv = -3.4e38f;
#pragma unroll
    for (int f = 0; f < 4; ++f) {
        const int kb = ckb + 16 * f + 4 * kg;
        const float4 m2v = *(const float4*)(mu2 + kb);
        const float4 rtv = *(const float4*)(rtau + kb);
        const float4 ltv = *(const float4*)(ltau + kb);
        const float4 vlv = *(const float4*)(vldf + kb);
#pragma unroll
        for (int r = 0; r < 4; ++r) {
            const float m2 = (&m2v.x)[r];
            const float d2 = fmaxf(fmaf(-2.0f, acc[f][r], q + m2), 0.f);
            const float dist = -6.25f * sqrtf(d2);       // 100/sqrt(256)
            const float sim = ((&vlv.x)[r] > 0.5f) ? dist : -1.0e12f;
            simv[4 * f + r] = sim;
            lpv[4 * f + r] = fmaf(sim, (&rtv.x)[r], -(&ltv.x)[r]);
            mxv = fmaxf(mxv, 0.5f * sim);
        }
    }
    mxv = fmaxf(mxv, shfl_xor_f(mxv, 16));
    mxv = fmaxf(mxv, shfl_xor_f(mxv, 32));
    float se = 0.f, sl = 0.f;
#pragma unroll
    for (int i = 0; i < 16; ++i) {
        const float e = __expf(fmaf(0.5f, simv[i], -mxv));
        se += e;
        sl = fmaf(e, lpv[i], sl);
    }
    se += shfl_xor_f(se, 16); se += shfl_xor_f(se, 32);
    sl += shfl_xor_f(sl, 16); sl += shfl_xor_f(sl, 32);
    const int slot = slot0 + 16 * w + n16;
    float res = (kg == 0 && slot <= relast) ? (-sl / se) : 0.f;
    res += shfl_xor_f(res, 1);
    res += shfl_xor_f(res, 2);
    res += shfl_xor_f(res, 4);
    res += shfl_xor_f(res, 8);
    if (lane == 0) wpart[g * 4 + w] = res;
}

// ---- K_E: deterministic per-class reduce -> loss ----
__global__ void k_final(const float* __restrict__ wpart, const int* __restrict__ ps,
                        const int* __restrict__ cnt, float* __restrict__ out)
{
    __shared__ float seg[CNUM];
    const int t = threadIdx.x;
    if (t < CNUM) {
        float s = 0.f;
        const int b0 = ps[t] >> 6, b1 = ps[t + 1] >> 6;
        for (int b = b0; b < b1; b++) {
            const float4 v = *(const float4*)(wpart + 4 * b);
            s += ((v.x + v.y) + (v.z + v.w));
        }
        seg[t] = s;
    }
    __syncthreads();
    if (t == 0) {
        float loss = 0.f;
        for (int c = 0; c < CNUM; c++) {
            const float cc = (float)cnt[c];
            if (cc > 0.f) loss += seg[c] / fmaxf(cc, 1.0f);
        }
        out[0] = loss;
    }
}

extern "C" void kernel_launch(void* const* d_in, const int* in_sizes, int n_in,
                              void* d_out, int out_size, void* d_ws, size_t ws_size,
                              hipStream_t stream)
{
    const float* data     = (const float*)d_in[0];
    const int*   labels   = (const int*)d_in[1];
    const float* mu       = (const float*)d_in[2];
    const float* exp_temp = (const float*)d_in[3];
    const float* med      = (const float*)d_in[4];
    const float* stdv     = (const float*)d_in[5];
    const float* runa     = (const float*)d_in[6];
    const float* runb     = (const float*)d_in[7];
    float* out = (float*)d_out;
    const int N = in_sizes[0] / DDIM;
    const int SNB = (N + 255) / 256;                     // scatter/hist blocks
    const int idx_slots = N + CNUM * 64;
    const int NB = (idx_slots + 63) / 64;                // mfma blocks

    char* w = (char*)d_ws;
    float* mu2  = (float*)w; w += (size_t)CNUM * KNUM * 4;
    float* rtau = (float*)w; w += (size_t)CNUM * KNUM * 4;
    float* ltau = (float*)w; w += (size_t)CNUM * KNUM * 4;
    float* vldf = (float*)w; w += (size_t)CNUM * KNUM * 4;
    float* rstd = (float*)w; w += (size_t)DDIM * 4;
    float* mrs  = (float*)w; w += (size_t)DDIM * 4;
    unsigned short* mubf = (unsigned short*)w; w += (size_t)CNUM * KNUM * DDIM * 2;
    int* bc  = (int*)w; w += (size_t)SNB * CNUM * 4;
    int* sb  = (int*)w; w += (size_t)SNB * CNUM * 4;
    int* cnt = (int*)w; w += 64 * 4;
    int* ps  = (int*)w; w += 64 * 4;
    int* blk2cls = (int*)w; w += (size_t)NB * 4;
    float* wp = (float*)w; w += (size_t)NB * 4 * 4;
    w = (char*)(((size_t)w + 511) & ~(size_t)511);
    unsigned short* xs = (unsigned short*)w; w += (size_t)idx_slots * DDIM * 2;

    k_setup<<<dim3(320 + SNB), dim3(256), 0, stream>>>(
        mu, exp_temp, runa, runb, med, stdv, labels, N,
        mu2, rtau, ltau, vldf, rstd, mrs, mubf, bc);
    k_scan<<<dim3(1), dim3(256), 0, stream>>>(bc, SNB, cnt, ps, sb, blk2cls);
    k_scnorm<<<dim3(SNB), dim3(256), 0, stream>>>(data, mrs, rstd, labels, N, sb, xs);
    k_mfma<<<dim3(NB), dim3(256), 0, stream>>>(
        xs, mubf, mu2, rtau, ltau, vldf, ps, cnt, blk2cls, wp);
    k_final<<<dim3(1), dim3(32), 0, stream>>>(wp, ps, cnt, out);
}